// Round 2
// baseline (13714.583 us; speedup 1.0000x reference)
//
#include <hip/hip_runtime.h>
#include <hip/hip_bf16.h>

typedef __attribute__((ext_vector_type(8))) short bhalf8;
typedef __attribute__((ext_vector_type(4))) float fvec4;

static __device__ __forceinline__ unsigned short f2bf(float f) {
  unsigned u = __builtin_bit_cast(unsigned, f);
  u = (u + 0x7fffu + ((u >> 16) & 1u)) >> 16;   // round-to-nearest-even
  return (unsigned short)u;
}
static __device__ __forceinline__ float tanh_fast(float x) {
  x = fminf(12.f, fmaxf(-12.f, x));
  float e = __expf(2.f * x);
  return (e - 1.f) / (e + 1.f);
}
static __device__ __forceinline__ fvec4 tanh4(fvec4 v) {
  fvec4 r;
  r[0] = tanh_fast(v[0]); r[1] = tanh_fast(v[1]);
  r[2] = tanh_fast(v[2]); r[3] = tanh_fast(v[3]);
  return r;
}
static __device__ __forceinline__ bhalf8 load_w8(const float* p) {
  fvec4 a = *(const fvec4*)p;
  fvec4 b = *(const fvec4*)(p + 4);
  bhalf8 r;
  r[0] = (short)f2bf(a[0]); r[1] = (short)f2bf(a[1]);
  r[2] = (short)f2bf(a[2]); r[3] = (short)f2bf(a[3]);
  r[4] = (short)f2bf(b[0]); r[5] = (short)f2bf(b[1]);
  r[6] = (short)f2bf(b[2]); r[7] = (short)f2bf(b[3]);
  return r;
}

#define MFMA16(a, b, c) __builtin_amdgcn_mfma_f32_16x16x32_bf16((a), (b), (c), 0, 0, 0)

// Persistent kernel, plain launch (grid=256 <= 1 block/CU x 256 CU: whole grid is
// HW-resident, so the group-local spin barrier cannot deadlock).
// WG = (group, member): group = 32 batch rows, member = 64 H-cols. Wave owns 16 cols;
// all weights for its cols live in registers as MFMA B-fragments. 16 WGs of a group
// exchange z12 / z2 tiles via ping-pong ws buffers + monotonic-counter barrier.
extern "C" __global__ void __launch_bounds__(256, 1)
alarm_rnn_persist(const float* __restrict__ X, const float* __restrict__ Win1,
                  const float* __restrict__ bin1, const float* __restrict__ Wrec1,
                  const float* __restrict__ Win2, const float* __restrict__ bin2,
                  const float* __restrict__ Wrec2, const float* __restrict__ Wout,
                  const float* __restrict__ bout, float* __restrict__ out,
                  unsigned* bar, unsigned short* gbuf0, unsigned short* gbuf1,
                  unsigned short* z2b0, unsigned short* z2b1, float* z1buf)
{
  constexpr int kL = 512, kI = 256, kH = 1024;
  extern __shared__ char smem[];  // [0,64K) z12 | [64K,80K) X(bf16) | [80K,144K) z2

  const int tid = threadIdx.x, bid = blockIdx.x;
  const int grp = bid >> 4, memb = bid & 15;
  const int lane = tid & 63, wave = tid >> 6;
  const int row16 = lane & 15, kq = lane >> 4;
  const int hcol = memb * 64 + wave * 16 + row16;
  const int brow0 = grp * 32;

  // ---- one-time: weights -> registers (B-fragment: lane holds W[hcol, kq*8+j (+32*kk)]) ----
  bhalf8 w1[32], w2[32], wi1[8], wi2[8];
  {
    const float* p1 = Wrec1 + (size_t)hcol * kH + kq * 8;
    const float* p2 = Wrec2 + (size_t)hcol * kH + kq * 8;
#pragma unroll
    for (int kk = 0; kk < 32; ++kk) {
      w1[kk] = load_w8(p1 + kk * 32);
      w2[kk] = load_w8(p2 + kk * 32);
    }
    const float* q1 = Win1 + (size_t)hcol * kI + kq * 8;
    const float* q2 = Win2 + (size_t)hcol * kI + kq * 8;
#pragma unroll
    for (int kk = 0; kk < 8; ++kk) {
      wi1[kk] = load_w8(q1 + kk * 32);
      wi2[kk] = load_w8(q2 + kk * 32);
    }
  }
  const float bv1 = bin1[hcol];
  const float bv2 = bin2[hcol];
  fvec4 z2r0 = {0.f, 0.f, 0.f, 0.f}, z2r1 = {0.f, 0.f, 0.f, 0.f};

  for (int l = 0; l < kL; ++l) {
    const bool even = ((l & 1) == 0);
    const int e = l >> 1;

    // ---- stage z12 tile (32 x 1024 bf16) -> LDS, XOR-swizzled ----
    {
      const unsigned short* zsrc = (l & 1) ? gbuf1 : gbuf0;
      uint4 tmp[16];
#pragma unroll
      for (int it = 0; it < 16; ++it) {
        int c = it * 256 + tid;
        int r = c >> 7, cb = (c & 127) * 16;
        tmp[it] = *(const uint4*)(zsrc + (size_t)(brow0 + r) * kH + (cb >> 1));
      }
#pragma unroll
      for (int it = 0; it < 16; ++it) {
        int c = it * 256 + tid;
        int r = c >> 7, cb = (c & 127) * 16;
        *(uint4*)(smem + (r << 11) + (cb ^ ((r & 7) << 4))) = tmp[it];
      }
    }
    // ---- stage X tile (32 x 256 f32 -> bf16) ----
    {
      int r = tid >> 3, q = tid & 7;
      const float* xp = X + (size_t)(brow0 + r) * (kL * kI) + (size_t)l * kI;
      fvec4 xv[8];
#pragma unroll
      for (int j = 0; j < 8; ++j) xv[j] = *(const fvec4*)(xp + q * 4 + j * 32);
#pragma unroll
      for (int j = 0; j < 8; ++j) {
        int i0 = q * 4 + j * 32;
        ushort4 pk;
        pk.x = f2bf(xv[j][0]); pk.y = f2bf(xv[j][1]);
        pk.z = f2bf(xv[j][2]); pk.w = f2bf(xv[j][3]);
        *(ushort4*)(smem + 65536 + (r << 9) + ((i0 * 2) ^ ((r & 7) << 4))) = pk;
      }
    }
    // ---- stage z2 tile on even steps (ping-pong: read buffer written 2 steps ago) ----
    if (even) {
      const unsigned short* z2src = (e & 1) ? z2b1 : z2b0;
      uint4 tmp[16];
#pragma unroll
      for (int it = 0; it < 16; ++it) {
        int c = it * 256 + tid;
        int r = c >> 7, cb = (c & 127) * 16;
        tmp[it] = *(const uint4*)(z2src + (size_t)(brow0 + r) * kH + (cb >> 1));
      }
#pragma unroll
      for (int it = 0; it < 16; ++it) {
        int c = it * 256 + tid;
        int r = c >> 7, cb = (c & 127) * 16;
        *(uint4*)(smem + 81920 + (r << 11) + (cb ^ ((r & 7) << 4))) = tmp[it];
      }
    }
    __syncthreads();

    const int sw = (row16 & 7) << 4;

    // ---- z1 = tanh(b1 + X*Win1^T + z12*Wrec1^T), 2 m-tiles, N=16/wave ----
    fvec4 acc0 = {bv1, bv1, bv1, bv1}, acc1 = acc0;
#pragma unroll
    for (int kk = 0; kk < 8; ++kk) {
      int cb = kk * 64 + kq * 16;
      bhalf8 a0 = *(const bhalf8*)(smem + 65536 + (row16 << 9) + (cb ^ sw));
      bhalf8 a1 = *(const bhalf8*)(smem + 65536 + ((16 + row16) << 9) + (cb ^ sw));
      acc0 = MFMA16(a0, wi1[kk], acc0);
      acc1 = MFMA16(a1, wi1[kk], acc1);
    }
#pragma unroll
    for (int kk = 0; kk < 32; ++kk) {
      int cb = kk * 64 + kq * 16;
      bhalf8 a0 = *(const bhalf8*)(smem + (row16 << 11) + (cb ^ sw));
      bhalf8 a1 = *(const bhalf8*)(smem + ((16 + row16) << 11) + (cb ^ sw));
      acc0 = MFMA16(a0, w1[kk], acc0);
      acc1 = MFMA16(a1, w1[kk], acc1);
    }
    fvec4 z1n0 = tanh4(acc0), z1n1 = tanh4(acc1);

    // ---- even steps: z2 = tanh(b2 + X*Win2^T + z2*Wrec2^T) ----
    if (even) {
      fvec4 bacc0 = {bv2, bv2, bv2, bv2}, bacc1 = bacc0;
#pragma unroll
      for (int kk = 0; kk < 8; ++kk) {
        int cb = kk * 64 + kq * 16;
        bhalf8 a0 = *(const bhalf8*)(smem + 65536 + (row16 << 9) + (cb ^ sw));
        bhalf8 a1 = *(const bhalf8*)(smem + 65536 + ((16 + row16) << 9) + (cb ^ sw));
        bacc0 = MFMA16(a0, wi2[kk], bacc0);
        bacc1 = MFMA16(a1, wi2[kk], bacc1);
      }
#pragma unroll
      for (int kk = 0; kk < 32; ++kk) {
        int cb = kk * 64 + kq * 16;
        bhalf8 a0 = *(const bhalf8*)(smem + 81920 + (row16 << 11) + (cb ^ sw));
        bhalf8 a1 = *(const bhalf8*)(smem + 81920 + ((16 + row16) << 11) + (cb ^ sw));
        bacc0 = MFMA16(a0, w2[kk], bacc0);
        bacc1 = MFMA16(a1, w2[kk], bacc1);
      }
      z2r0 = tanh4(bacc0);
      z2r1 = tanh4(bacc1);
      unsigned short* z2dst = (e & 1) ? z2b0 : z2b1;
#pragma unroll
      for (int i = 0; i < 4; ++i) {
        z2dst[(size_t)(brow0 + kq * 4 + i) * kH + hcol] = f2bf(z2r0[i]);
        z2dst[(size_t)(brow0 + 16 + kq * 4 + i) * kH + hcol] = f2bf(z2r1[i]);
      }
    }

    // ---- write z12 = z1 + z2 for next step (C/D layout: col=lane&15, row=kq*4+i) ----
    if (l < kL - 1) {
      unsigned short* dst = (l & 1) ? gbuf0 : gbuf1;
#pragma unroll
      for (int i = 0; i < 4; ++i) {
        dst[(size_t)(brow0 + kq * 4 + i) * kH + hcol] = f2bf(z1n0[i] + z2r0[i]);
        dst[(size_t)(brow0 + 16 + kq * 4 + i) * kH + hcol] = f2bf(z1n1[i] + z2r1[i]);
      }
    } else {
#pragma unroll
      for (int i = 0; i < 4; ++i) {
        z1buf[(size_t)(brow0 + kq * 4 + i) * kH + hcol] = z1n0[i];
        z1buf[(size_t)(brow0 + 16 + kq * 4 + i) * kH + hcol] = z1n1[i];
      }
    }

    // ---- group barrier: release stores, arrive, poll, acquire ----
    __syncthreads();  // all waves' stores issued & vmcnt-drained before arrive
    if (tid == 0) {
      __hip_atomic_fetch_add(&bar[grp * 32], 1u, __ATOMIC_RELEASE, __HIP_MEMORY_SCOPE_AGENT);
      unsigned tgt = 16u * (unsigned)(l + 1);
      while (__hip_atomic_load(&bar[grp * 32], __ATOMIC_RELAXED, __HIP_MEMORY_SCOPE_AGENT) < tgt)
        __builtin_amdgcn_s_sleep(8);
      __threadfence();  // acquire: invalidate L1/L2 so staged reads see remote tiles
    }
    __syncthreads();
  }

  // ---- epilogue: out[b] = tanh(z1[b,:] . Wout + bout), one WG per group ----
  if (memb == 0) {
    int r = tid >> 3, q = tid & 7;
    const float* zr = z1buf + (size_t)(brow0 + r) * kH;
    float s = 0.f;
#pragma unroll 8
    for (int h = q * 128; h < q * 128 + 128; ++h) s += zr[h] * Wout[h];
    s += __shfl_xor(s, 1);
    s += __shfl_xor(s, 2);
    s += __shfl_xor(s, 4);
    if (q == 0) out[brow0 + r] = tanh_fast(s + bout[0]);
  }
}

extern "C" void kernel_launch(void* const* d_in, const int* in_sizes, int n_in,
                              void* d_out, int out_size, void* d_ws, size_t ws_size,
                              hipStream_t stream) {
  const float* X = (const float*)d_in[0];
  const float* Win1 = (const float*)d_in[1];
  const float* bin1 = (const float*)d_in[2];
  const float* Wrec1 = (const float*)d_in[3];
  const float* Win2 = (const float*)d_in[4];
  const float* bin2 = (const float*)d_in[5];
  const float* Wrec2 = (const float*)d_in[6];
  const float* Wout = (const float*)d_in[7];
  const float* bout = (const float*)d_in[8];
  float* out = (float*)d_out;

  char* ws = (char*)d_ws;
  unsigned* bar = (unsigned*)ws;                                     // 16 groups * 128B
  unsigned short* gbuf0 = (unsigned short*)(ws + 4096);              // 1 MB z12 ping
  unsigned short* gbuf1 = (unsigned short*)(ws + 4096 + (1 << 20));  // 1 MB z12 pong
  unsigned short* z2b0 = (unsigned short*)(ws + 4096 + (2 << 20));   // 1 MB z2 ping
  unsigned short* z2b1 = (unsigned short*)(ws + 4096 + (3 << 20));   // 1 MB z2 pong
  float* z1buf = (float*)(ws + 4096 + (4 << 20));                    // 2 MB final z1 (f32)

  hipMemsetAsync(bar, 0, 4096, stream);
  hipMemsetAsync(gbuf0, 0, (size_t)512 * 1024 * 2, stream);  // z12(l=0) = 0
  hipMemsetAsync(z2b0, 0, (size_t)512 * 1024 * 2, stream);   // z2(l=0)  = 0

  hipFuncSetAttribute((const void*)alarm_rnn_persist,
                      hipFuncAttributeMaxDynamicSharedMemorySize, 147456);

  alarm_rnn_persist<<<dim3(256), dim3(256), 147456, stream>>>(
      X, Win1, bin1, Wrec1, Win2, bin2, Wrec2, Wout, bout, out,
      bar, gbuf0, gbuf1, z2b0, z2b1, z1buf);
}

// Round 4
// 6243.457 us; speedup vs baseline: 2.1966x; 2.1966x over previous
//
#include <hip/hip_runtime.h>
#include <hip/hip_bf16.h>

typedef __attribute__((ext_vector_type(8))) short bhalf8;
typedef __attribute__((ext_vector_type(4))) float fvec4;
typedef __attribute__((ext_vector_type(4))) unsigned u32x4;

static __device__ __forceinline__ unsigned short f2bf(float f) {
  unsigned u = __builtin_bit_cast(unsigned, f);
  u = (u + 0x7fffu + ((u >> 16) & 1u)) >> 16;   // round-to-nearest-even
  return (unsigned short)u;
}
static __device__ __forceinline__ float tanh_fast(float x) {
  x = fminf(12.f, fmaxf(-12.f, x));
  float e = __expf(2.f * x);
  return (e - 1.f) / (e + 1.f);
}
static __device__ __forceinline__ fvec4 tanh4(fvec4 v) {
  fvec4 r;
  r[0] = tanh_fast(v[0]); r[1] = tanh_fast(v[1]);
  r[2] = tanh_fast(v[2]); r[3] = tanh_fast(v[3]);
  return r;
}
static __device__ __forceinline__ bhalf8 load_w8(const float* p) {
  fvec4 a = *(const fvec4*)p;
  fvec4 b = *(const fvec4*)(p + 4);
  bhalf8 r;
  r[0] = (short)f2bf(a[0]); r[1] = (short)f2bf(a[1]);
  r[2] = (short)f2bf(a[2]); r[3] = (short)f2bf(a[3]);
  r[4] = (short)f2bf(b[0]); r[5] = (short)f2bf(b[1]);
  r[6] = (short)f2bf(b[2]); r[7] = (short)f2bf(b[3]);
  return r;
}

// ---- fabric-coherent (cross-XCD) accesses: sc0|sc1 bypasses L1 + XCD-L2; the
// ---- coherence point is the memory-side Infinity Cache. Pure inline asm — no
// ---- buffer-rsrc builtins. Loads are invisible to compiler waitcnt tracking, so
// ---- every consumer is preceded by an explicit s_waitcnt vmcnt(0) (memory-
// ---- clobbered, which also orders the following ds_write/flag ops).
static __device__ __forceinline__ void st_short_coh(unsigned short* p, unsigned v) {
  asm volatile("global_store_short %0, %1, off sc0 sc1" :: "v"(p), "v"(v) : "memory");
}
static __device__ __forceinline__ void st_f32_coh(float* p, float v) {
  asm volatile("global_store_dword %0, %1, off sc0 sc1" :: "v"(p), "v"(v) : "memory");
}
static __device__ __forceinline__ void st_u32_coh(unsigned* p, unsigned v) {
  asm volatile("global_store_dword %0, %1, off sc0 sc1" :: "v"(p), "v"(v) : "memory");
}
static __device__ __forceinline__ u32x4 ld16_coh(const void* p) {
  u32x4 v;
  asm volatile("global_load_dwordx4 %0, %1, off sc0 sc1" : "=v"(v) : "v"(p) : "memory");
  return v;
}
static __device__ __forceinline__ unsigned ld_u32_coh(const unsigned* p) {
  unsigned v;
  asm volatile("global_load_dword %0, %1, off sc0 sc1\n\ts_waitcnt vmcnt(0)"
               : "=v"(v) : "v"(p) : "memory");
  return v;
}
static __device__ __forceinline__ float ld_f32_coh(const float* p) {
  float v;
  asm volatile("global_load_dword %0, %1, off sc0 sc1\n\ts_waitcnt vmcnt(0)"
               : "=v"(v) : "v"(p) : "memory");
  return v;
}

#define MFMA16(a, b, c) __builtin_amdgcn_mfma_f32_16x16x32_bf16((a), (b), (c), 0, 0, 0)

// Persistent kernel. Grid 256 WGs x 256 thr (1 WG/CU -> whole grid HW-resident, spin
// barrier cannot deadlock). WG = (group, member): group = 32 batch rows, member = 64
// H-cols. Wave owns 16 cols; weights live in registers as MFMA B-fragments. 16 WGs of
// a group exchange z12/z2 via fabric-coherent stores/loads + per-WG monotonic flags.
extern "C" __global__ void __launch_bounds__(256, 1)
alarm_rnn_persist(const float* __restrict__ X, const float* __restrict__ Win1,
                  const float* __restrict__ bin1, const float* __restrict__ Wrec1,
                  const float* __restrict__ Win2, const float* __restrict__ bin2,
                  const float* __restrict__ Wrec2, const float* __restrict__ Wout,
                  const float* __restrict__ bout, float* __restrict__ out,
                  unsigned* flags, unsigned short* gbuf0, unsigned short* gbuf1,
                  unsigned short* z2b0, unsigned short* z2b1, float* z1buf)
{
  constexpr int kL = 512, kI = 256, kH = 1024;
  extern __shared__ char smem[];  // [0,64K) z12 | [64K,80K) X(bf16) | [80K,144K) z2

  const int tid = threadIdx.x, bid = blockIdx.x;
  const int grp = bid >> 4, memb = bid & 15;
  const int lane = tid & 63;
  const int row16 = lane & 15, kq = lane >> 4;
  const int hcol = memb * 64 + (tid >> 6) * 16 + row16;
  const int brow0 = grp * 32;

  // ---- one-time: weights -> registers (B-fragment: lane holds W[hcol, kq*8+j (+32*kk)]) ----
  bhalf8 w1[32], w2[32], wi1[8], wi2[8];
  {
    const float* p1 = Wrec1 + (size_t)hcol * kH + kq * 8;
    const float* p2 = Wrec2 + (size_t)hcol * kH + kq * 8;
#pragma unroll
    for (int kk = 0; kk < 32; ++kk) {
      w1[kk] = load_w8(p1 + kk * 32);
      w2[kk] = load_w8(p2 + kk * 32);
    }
    const float* q1 = Win1 + (size_t)hcol * kI + kq * 8;
    const float* q2 = Win2 + (size_t)hcol * kI + kq * 8;
#pragma unroll
    for (int kk = 0; kk < 8; ++kk) {
      wi1[kk] = load_w8(q1 + kk * 32);
      wi2[kk] = load_w8(q2 + kk * 32);
    }
  }
  const float bv1 = bin1[hcol];
  const float bv2 = bin2[hcol];
  fvec4 z2r0 = {0.f, 0.f, 0.f, 0.f}, z2r1 = {0.f, 0.f, 0.f, 0.f};

  // ---- prologue: stage X(l=0) tile (32 x 256 f32 -> bf16) into LDS ----
  {
    int r = tid >> 3, q = tid & 7;
    const float* xp = X + (size_t)(brow0 + r) * (kL * kI);
    fvec4 xv[8];
#pragma unroll
    for (int j = 0; j < 8; ++j) xv[j] = *(const fvec4*)(xp + q * 4 + j * 32);
#pragma unroll
    for (int j = 0; j < 8; ++j) {
      int i0 = q * 4 + j * 32;
      ushort4 pk;
      pk.x = f2bf(xv[j][0]); pk.y = f2bf(xv[j][1]);
      pk.z = f2bf(xv[j][2]); pk.w = f2bf(xv[j][3]);
      *(ushort4*)(smem + 65536 + (r << 9) + ((i0 * 2) ^ ((r & 7) << 4))) = pk;
    }
  }

  for (int l = 0; l < kL; ++l) {
    const bool even = ((l & 1) == 0);
    const int e = l >> 1;

    // ---- stage z12 tile (32 x 1024 bf16) -> LDS, XOR-swizzled (coherent loads) ----
    {
      const unsigned short* zsrc = (l & 1) ? gbuf1 : gbuf0;
      u32x4 tmp[16];
#pragma unroll
      for (int it = 0; it < 16; ++it) {
        int c = it * 256 + tid;
        int r = c >> 7, cb = (c & 127) * 16;
        tmp[it] = ld16_coh((const char*)zsrc + (((size_t)(brow0 + r)) << 11) + cb);
      }
      asm volatile("s_waitcnt vmcnt(0)" ::: "memory");
      __builtin_amdgcn_sched_barrier(0);
#pragma unroll
      for (int it = 0; it < 16; ++it) {
        int c = it * 256 + tid;
        int r = c >> 7, cb = (c & 127) * 16;
        *(u32x4*)(smem + (r << 11) + (cb ^ ((r & 7) << 4))) = tmp[it];
      }
    }
    // ---- stage z2 tile on even steps (ping-pong buffer written 2 steps ago) ----
    if (even) {
      const unsigned short* z2src = (e & 1) ? z2b1 : z2b0;
      u32x4 tmp[16];
#pragma unroll
      for (int it = 0; it < 16; ++it) {
        int c = it * 256 + tid;
        int r = c >> 7, cb = (c & 127) * 16;
        tmp[it] = ld16_coh((const char*)z2src + (((size_t)(brow0 + r)) << 11) + cb);
      }
      asm volatile("s_waitcnt vmcnt(0)" ::: "memory");
      __builtin_amdgcn_sched_barrier(0);
#pragma unroll
      for (int it = 0; it < 16; ++it) {
        int c = it * 256 + tid;
        int r = c >> 7, cb = (c & 127) * 16;
        *(u32x4*)(smem + 81920 + (r << 11) + (cb ^ ((r & 7) << 4))) = tmp[it];
      }
    }
    __syncthreads();  // #1: staging visible to all waves

    const int sw = (row16 & 7) << 4;

    // ---- z1 = tanh(b1 + X*Win1^T + z12*Wrec1^T), 2 m-tiles, N=16/wave ----
    fvec4 acc0 = {bv1, bv1, bv1, bv1}, acc1 = acc0;
#pragma unroll
    for (int kk = 0; kk < 8; ++kk) {
      int cb = kk * 64 + kq * 16;
      bhalf8 a0 = *(const bhalf8*)(smem + 65536 + (row16 << 9) + (cb ^ sw));
      bhalf8 a1 = *(const bhalf8*)(smem + 65536 + ((16 + row16) << 9) + (cb ^ sw));
      acc0 = MFMA16(a0, wi1[kk], acc0);
      acc1 = MFMA16(a1, wi1[kk], acc1);
    }
#pragma unroll
    for (int kk = 0; kk < 32; ++kk) {
      int cb = kk * 64 + kq * 16;
      bhalf8 a0 = *(const bhalf8*)(smem + (row16 << 11) + (cb ^ sw));
      bhalf8 a1 = *(const bhalf8*)(smem + ((16 + row16) << 11) + (cb ^ sw));
      acc0 = MFMA16(a0, w1[kk], acc0);
      acc1 = MFMA16(a1, w1[kk], acc1);
    }
    fvec4 z1n0 = tanh4(acc0), z1n1 = tanh4(acc1);

    // ---- even steps: z2 = tanh(b2 + X*Win2^T + z2*Wrec2^T) ----
    if (even) {
      fvec4 bacc0 = {bv2, bv2, bv2, bv2}, bacc1 = bacc0;
#pragma unroll
      for (int kk = 0; kk < 8; ++kk) {
        int cb = kk * 64 + kq * 16;
        bhalf8 a0 = *(const bhalf8*)(smem + 65536 + (row16 << 9) + (cb ^ sw));
        bhalf8 a1 = *(const bhalf8*)(smem + 65536 + ((16 + row16) << 9) + (cb ^ sw));
        bacc0 = MFMA16(a0, wi2[kk], bacc0);
        bacc1 = MFMA16(a1, wi2[kk], bacc1);
      }
#pragma unroll
      for (int kk = 0; kk < 32; ++kk) {
        int cb = kk * 64 + kq * 16;
        bhalf8 a0 = *(const bhalf8*)(smem + 81920 + (row16 << 11) + (cb ^ sw));
        bhalf8 a1 = *(const bhalf8*)(smem + 81920 + ((16 + row16) << 11) + (cb ^ sw));
        bacc0 = MFMA16(a0, w2[kk], bacc0);
        bacc1 = MFMA16(a1, w2[kk], bacc1);
      }
      z2r0 = tanh4(bacc0);
      z2r1 = tanh4(bacc1);
      unsigned short* z2dst = (e & 1) ? z2b0 : z2b1;
#pragma unroll
      for (int i = 0; i < 4; ++i) {
        st_short_coh(z2dst + (size_t)(brow0 + kq * 4 + i) * kH + hcol, f2bf(z2r0[i]));
        st_short_coh(z2dst + (size_t)(brow0 + 16 + kq * 4 + i) * kH + hcol, f2bf(z2r1[i]));
      }
    }

    // ---- write z12 = z1 + z2 for next step (C/D layout: col=lane&15, row=kq*4+i) ----
    if (l < kL - 1) {
      unsigned short* dst = (l & 1) ? gbuf0 : gbuf1;
#pragma unroll
      for (int i = 0; i < 4; ++i) {
        st_short_coh(dst + (size_t)(brow0 + kq * 4 + i) * kH + hcol, f2bf(z1n0[i] + z2r0[i]));
        st_short_coh(dst + (size_t)(brow0 + 16 + kq * 4 + i) * kH + hcol, f2bf(z1n1[i] + z2r1[i]));
      }
    } else {
#pragma unroll
      for (int i = 0; i < 4; ++i) {
        st_f32_coh(z1buf + (size_t)(brow0 + kq * 4 + i) * kH + hcol, z1n0[i]);
        st_f32_coh(z1buf + (size_t)(brow0 + 16 + kq * 4 + i) * kH + hcol, z1n1[i]);
      }
    }

    // ---- drain own stores, block-sync, publish flag ----
    asm volatile("s_waitcnt vmcnt(0)" ::: "memory");
    __syncthreads();  // #2: all waves' coherent stores complete
    if (tid == 0) st_u32_coh(flags + grp * 16 + memb, (unsigned)(l + 1));

    // ---- issue X(l+1) loads so they fly during the poll ----
    fvec4 xv[8];
    const int xr = tid >> 3, xq = tid & 7;
    if (l + 1 < kL) {
      const float* xp = X + (size_t)(brow0 + xr) * (kL * kI) + (size_t)(l + 1) * kI;
#pragma unroll
      for (int j = 0; j < 8; ++j) xv[j] = *(const fvec4*)(xp + xq * 4 + j * 32);
    }

    // ---- poll sibling flags (own slice already drained -> skip self) ----
    {
      const unsigned tgt = (unsigned)(l + 1);
      const unsigned* fp = flags + grp * 16 + (lane & 15);
      for (;;) {
        unsigned v = (lane < 16) ? ld_u32_coh(fp) : tgt;
        bool ok = (lane >= 16) || ((lane & 15) == memb) || (v >= tgt);
        if (__all(ok)) break;
        __builtin_amdgcn_s_sleep(1);
      }
      __builtin_amdgcn_sched_barrier(0);
    }

    // ---- finish X(l+1) staging (cvt + swizzled LDS write) ----
    if (l + 1 < kL) {
#pragma unroll
      for (int j = 0; j < 8; ++j) {
        int i0 = xq * 4 + j * 32;
        ushort4 pk;
        pk.x = f2bf(xv[j][0]); pk.y = f2bf(xv[j][1]);
        pk.z = f2bf(xv[j][2]); pk.w = f2bf(xv[j][3]);
        *(ushort4*)(smem + 65536 + (xr << 9) + ((i0 * 2) ^ ((xr & 7) << 4))) = pk;
      }
    }
  }

  // ---- epilogue: out[b] = tanh(z1[b,:] . Wout + bout), one WG per group ----
  if (memb == 0) {
    int r = tid >> 3, q = tid & 7;
    const float* zr = z1buf + (size_t)(brow0 + r) * kH;
    float s = 0.f;
    for (int h = q * 128; h < q * 128 + 128; ++h) s += ld_f32_coh(zr + h) * Wout[h];
    s += __shfl_xor(s, 1);
    s += __shfl_xor(s, 2);
    s += __shfl_xor(s, 4);
    if (q == 0) out[brow0 + r] = tanh_fast(s + bout[0]);
  }
}

extern "C" void kernel_launch(void* const* d_in, const int* in_sizes, int n_in,
                              void* d_out, int out_size, void* d_ws, size_t ws_size,
                              hipStream_t stream) {
  const float* X = (const float*)d_in[0];
  const float* Win1 = (const float*)d_in[1];
  const float* bin1 = (const float*)d_in[2];
  const float* Wrec1 = (const float*)d_in[3];
  const float* Win2 = (const float*)d_in[4];
  const float* bin2 = (const float*)d_in[5];
  const float* Wrec2 = (const float*)d_in[6];
  const float* Wout = (const float*)d_in[7];
  const float* bout = (const float*)d_in[8];
  float* out = (float*)d_out;

  char* ws = (char*)d_ws;
  unsigned* flags = (unsigned*)ws;                                   // 16 groups * 16 members
  unsigned short* gbuf0 = (unsigned short*)(ws + 4096);              // 1 MB z12 ping
  unsigned short* gbuf1 = (unsigned short*)(ws + 4096 + (1 << 20));  // 1 MB z12 pong
  unsigned short* z2b0 = (unsigned short*)(ws + 4096 + (2 << 20));   // 1 MB z2 ping
  unsigned short* z2b1 = (unsigned short*)(ws + 4096 + (3 << 20));   // 1 MB z2 pong
  float* z1buf = (float*)(ws + 4096 + (4 << 20));                    // 2 MB final z1 (f32)

  (void)hipMemsetAsync(flags, 0, 4096, stream);
  (void)hipMemsetAsync(gbuf0, 0, (size_t)512 * 1024 * 2, stream);  // z12(l=0) = 0
  (void)hipMemsetAsync(z2b0, 0, (size_t)512 * 1024 * 2, stream);   // z2(l=0)  = 0

  (void)hipFuncSetAttribute((const void*)alarm_rnn_persist,
                            hipFuncAttributeMaxDynamicSharedMemorySize, 147456);

  alarm_rnn_persist<<<dim3(256), dim3(256), 147456, stream>>>(
      X, Win1, bin1, Wrec1, Win2, bin2, Wrec2, Wout, bout, out,
      flags, gbuf0, gbuf1, z2b0, z2b1, z1buf);
}